// Round 4
// baseline (303.006 us; speedup 1.0000x reference)
//
#include <hip/hip_runtime.h>

// ---------------------------------------------------------------------------
// AttentionOT  (Nq=64, M=16, B=8, K=256, C=512)
//   Front (error-critical, feeds exp(20*sim)): bf16x3 split MFMA (Markidis).
//     l2norm eliminated: sim = (q.k)*rs_q*rs_k (scaling commutes out of dot).
//   Back half: plain bf16 MFMA, fp32->bf16 casts fused into GEMM staging.
//   Sinkhorn: P-layout + DPP row_ror reductions (no LDS round-trip,
//     no readlane) -- kills the round-3 latency chain at 2 waves/SIMD.
//   8 dispatches total (was 16).
// ---------------------------------------------------------------------------

typedef short   short8  __attribute__((ext_vector_type(8)));
typedef float   floatx4 __attribute__((ext_vector_type(4)));

static __device__ __forceinline__ float fastrcp(float x) {
    return __builtin_amdgcn_rcpf(x);
}
static __device__ __forceinline__ unsigned short f2bf(float f) {
    union { float f; unsigned u; } c; c.f = f;
    unsigned r = c.u + 0x7FFF + ((c.u >> 16) & 1);   // RNE
    return (unsigned short)(r >> 16);
}
static __device__ __forceinline__ float bf2f(unsigned short h) {
    union { unsigned u; float f; } c; c.u = (unsigned)h << 16;
    return c.f;
}

// ---------------------------------------------------------------------------
// q/k projection: Out = X @ W^T in ~fp32 (bf16x3), inputs fp32 split during
// LDS staging; epilogue writes split bf16 pair (hi,lo), rows optionally
// permuted (q: (n*16+m)*8+b -> b*1024+m*64+n).  128x128 tile, BK=32.
// ---------------------------------------------------------------------------
template <bool QPERM>
__global__ __launch_bounds__(256) void gemm_qkproj(
    const float* __restrict__ A, const float* __restrict__ B,
    unsigned short* __restrict__ dh, unsigned short* __restrict__ dl)
{
    __shared__ __align__(16) short Ash[128][40];
    __shared__ __align__(16) short Asl[128][40];
    __shared__ __align__(16) short Bsh[128][40];
    __shared__ __align__(16) short Bsl[128][40];

    const int tid  = threadIdx.x;
    const int lane = tid & 63, wv = tid >> 6;
    const int wr = (wv >> 1) * 64, wc = (wv & 1) * 64;
    const int i0 = blockIdx.x * 128, j0 = blockIdx.y * 128;

    floatx4 acc[4][4];
#pragma unroll
    for (int i = 0; i < 4; i++)
#pragma unroll
        for (int j = 0; j < 4; j++) acc[i][j] = {0.f, 0.f, 0.f, 0.f};

    const int sr = tid >> 1;          // 0..127
    const int sk = (tid & 1) * 16;    // 0 / 16
    const int fr = lane & 15, fq = (lane >> 4) * 8;

    for (int k0 = 0; k0 < 512; k0 += 32) {
        {
            const float* pa = A + (long)(i0 + sr) * 512 + k0 + sk;
            float x[16];
            *(float4*)&x[0]  = *(const float4*)(pa + 0);
            *(float4*)&x[4]  = *(const float4*)(pa + 4);
            *(float4*)&x[8]  = *(const float4*)(pa + 8);
            *(float4*)&x[12] = *(const float4*)(pa + 12);
            unsigned short h[16], l[16];
#pragma unroll
            for (int t = 0; t < 16; t++) {
                h[t] = f2bf(x[t]); l[t] = f2bf(x[t] - bf2f(h[t]));
            }
            *(short8*)&Ash[sr][sk]     = *(short8*)&h[0];
            *(short8*)&Ash[sr][sk + 8] = *(short8*)&h[8];
            *(short8*)&Asl[sr][sk]     = *(short8*)&l[0];
            *(short8*)&Asl[sr][sk + 8] = *(short8*)&l[8];
        }
        {
            const float* pb = B + (long)(j0 + sr) * 512 + k0 + sk;
            float x[16];
            *(float4*)&x[0]  = *(const float4*)(pb + 0);
            *(float4*)&x[4]  = *(const float4*)(pb + 4);
            *(float4*)&x[8]  = *(const float4*)(pb + 8);
            *(float4*)&x[12] = *(const float4*)(pb + 12);
            unsigned short h[16], l[16];
#pragma unroll
            for (int t = 0; t < 16; t++) {
                h[t] = f2bf(x[t]); l[t] = f2bf(x[t] - bf2f(h[t]));
            }
            *(short8*)&Bsh[sr][sk]     = *(short8*)&h[0];
            *(short8*)&Bsh[sr][sk + 8] = *(short8*)&h[8];
            *(short8*)&Bsl[sr][sk]     = *(short8*)&l[0];
            *(short8*)&Bsl[sr][sk + 8] = *(short8*)&l[8];
        }
        __syncthreads();
        short8 ah[4], al[4], bh[4], bl[4];
#pragma unroll
        for (int i = 0; i < 4; i++) {
            ah[i] = *(const short8*)&Ash[wr + i * 16 + fr][fq];
            al[i] = *(const short8*)&Asl[wr + i * 16 + fr][fq];
        }
#pragma unroll
        for (int j = 0; j < 4; j++) {
            bh[j] = *(const short8*)&Bsh[wc + j * 16 + fr][fq];
            bl[j] = *(const short8*)&Bsl[wc + j * 16 + fr][fq];
        }
#pragma unroll
        for (int i = 0; i < 4; i++)
#pragma unroll
            for (int j = 0; j < 4; j++) {
                acc[i][j] = __builtin_amdgcn_mfma_f32_16x16x32_bf16(ah[i], bh[j], acc[i][j], 0, 0, 0);
                acc[i][j] = __builtin_amdgcn_mfma_f32_16x16x32_bf16(ah[i], bl[j], acc[i][j], 0, 0, 0);
                acc[i][j] = __builtin_amdgcn_mfma_f32_16x16x32_bf16(al[i], bh[j], acc[i][j], 0, 0, 0);
            }
        __syncthreads();
    }

    const int cr = (lane >> 4) * 4, cc = lane & 15;
#pragma unroll
    for (int i = 0; i < 4; i++)
#pragma unroll
        for (int j = 0; j < 4; j++) {
            const int gj = j0 + wc + j * 16 + cc;
#pragma unroll
            for (int r = 0; r < 4; r++) {
                const int gi = i0 + wr + i * 16 + cr + r;
                long orow;
                if constexpr (QPERM)
                    orow = (long)((gi & 7) * 1024 + ((gi >> 3) & 15) * 64 + (gi >> 7));
                else
                    orow = gi;
                const float v = acc[i][j][r];
                const unsigned short h = f2bf(v);
                dh[orow * 512 + gj] = h;
                dl[orow * 512 + gj] = f2bf(v - bf2f(h));
            }
        }
}

// ---------------------------------------------------------------------------
// sim GEMM (bf16x3 on split pairs) with epilogue scale rs_k[i]*rs_q[j].
// Per batch b: A = k pair (256x512), B = q pair (1024x512), out fp32 256x1024.
// ---------------------------------------------------------------------------
__global__ __launch_bounds__(256) void gemm_sim(
    const short* __restrict__ Ah, const short* __restrict__ Al,
    const short* __restrict__ Bh, const short* __restrict__ Bl,
    float* __restrict__ Out, const float* __restrict__ rs)
{
    const int z = blockIdx.z;
    Ah += (long)z * 131072;  Al += (long)z * 131072;
    Bh += (long)z * 524288;  Bl += (long)z * 524288;
    Out += (long)z * 262144;
    const float* rsq = rs + (long)z * 1024;
    const float* rsk = rs + 8192 + (long)z * 256;

    __shared__ __align__(16) short Ash[128][40];
    __shared__ __align__(16) short Asl[128][40];
    __shared__ __align__(16) short Bsh[128][40];
    __shared__ __align__(16) short Bsl[128][40];

    const int tid  = threadIdx.x;
    const int lane = tid & 63, wv = tid >> 6;
    const int wr = (wv >> 1) * 64, wc = (wv & 1) * 64;
    const int i0 = blockIdx.x * 128, j0 = blockIdx.y * 128;

    floatx4 acc[4][4];
#pragma unroll
    for (int i = 0; i < 4; i++)
#pragma unroll
        for (int j = 0; j < 4; j++) acc[i][j] = {0.f, 0.f, 0.f, 0.f};

    const int srow = tid >> 2, sch = (tid & 3) * 8;
    const int fr = lane & 15, fq = (lane >> 4) * 8;

    for (int k0 = 0; k0 < 512; k0 += 32) {
#pragma unroll
        for (int p = 0; p < 2; p++) {
            const int r = srow + p * 64;
            const long ao = (long)(i0 + r) * 512 + k0 + sch;
            const long bo = (long)(j0 + r) * 512 + k0 + sch;
            *(short8*)&Ash[r][sch] = *(const short8*)(Ah + ao);
            *(short8*)&Asl[r][sch] = *(const short8*)(Al + ao);
            *(short8*)&Bsh[r][sch] = *(const short8*)(Bh + bo);
            *(short8*)&Bsl[r][sch] = *(const short8*)(Bl + bo);
        }
        __syncthreads();
        short8 ah[4], al[4], bh[4], bl[4];
#pragma unroll
        for (int i = 0; i < 4; i++) {
            ah[i] = *(const short8*)&Ash[wr + i * 16 + fr][fq];
            al[i] = *(const short8*)&Asl[wr + i * 16 + fr][fq];
        }
#pragma unroll
        for (int j = 0; j < 4; j++) {
            bh[j] = *(const short8*)&Bsh[wc + j * 16 + fr][fq];
            bl[j] = *(const short8*)&Bsl[wc + j * 16 + fr][fq];
        }
#pragma unroll
        for (int i = 0; i < 4; i++)
#pragma unroll
            for (int j = 0; j < 4; j++) {
                acc[i][j] = __builtin_amdgcn_mfma_f32_16x16x32_bf16(ah[i], bh[j], acc[i][j], 0, 0, 0);
                acc[i][j] = __builtin_amdgcn_mfma_f32_16x16x32_bf16(ah[i], bl[j], acc[i][j], 0, 0, 0);
                acc[i][j] = __builtin_amdgcn_mfma_f32_16x16x32_bf16(al[i], bh[j], acc[i][j], 0, 0, 0);
            }
        __syncthreads();
    }

    const int cr = (lane >> 4) * 4, cc = lane & 15;
#pragma unroll
    for (int i = 0; i < 4; i++)
#pragma unroll
        for (int j = 0; j < 4; j++) {
            const int gj = j0 + wc + j * 16 + cc;
            const float sq = rsq[gj];
#pragma unroll
            for (int r = 0; r < 4; r++) {
                const int gi = i0 + wr + i * 16 + cr + r;
                Out[(long)gi * 1024 + gj] = acc[i][j][r] * rsk[gi] * sq;
            }
        }
}

// ---------------------------------------------------------------------------
// Plain bf16 MFMA GEMM, 128x128 tile, BK=32; fp32 operands cast in staging.
// ---------------------------------------------------------------------------
template <bool AF32, bool BF32, bool OTRANS, bool BIAS, bool OPERM, bool OUT_BF16>
__global__ __launch_bounds__(256) void gemm_bf16(
    const void* __restrict__ Av, const void* __restrict__ Bv,
    const float* __restrict__ bias, void* __restrict__ OutV,
    int Kdim, int lda, int ldb, int ldo, long sA, long sB, long sO)
{
    __shared__ __align__(16) short As[128][40];
    __shared__ __align__(16) short Bs[128][40];

    const int tid  = threadIdx.x;
    const int lane = tid & 63, wv = tid >> 6;
    const int wr = (wv >> 1) * 64, wc = (wv & 1) * 64;
    const int i0 = blockIdx.x * 128, j0 = blockIdx.y * 128;

    floatx4 acc[4][4];
#pragma unroll
    for (int i = 0; i < 4; i++)
#pragma unroll
        for (int j = 0; j < 4; j++) acc[i][j] = {0.f, 0.f, 0.f, 0.f};

    const int sr2 = tid >> 1, sk2 = (tid & 1) * 16;
    const int sr4 = tid >> 2, sk4 = (tid & 3) * 8;
    const int fr = lane & 15, fq = (lane >> 4) * 8;

    for (int k0 = 0; k0 < Kdim; k0 += 32) {
        if constexpr (AF32) {
            const float* pa = (const float*)Av + (long)blockIdx.z * sA
                              + (long)(i0 + sr2) * lda + k0 + sk2;
            float x[16];
            *(float4*)&x[0]  = *(const float4*)(pa + 0);
            *(float4*)&x[4]  = *(const float4*)(pa + 4);
            *(float4*)&x[8]  = *(const float4*)(pa + 8);
            *(float4*)&x[12] = *(const float4*)(pa + 12);
            unsigned short h[16];
#pragma unroll
            for (int t = 0; t < 16; t++) h[t] = f2bf(x[t]);
            *(short8*)&As[sr2][sk2]     = *(short8*)&h[0];
            *(short8*)&As[sr2][sk2 + 8] = *(short8*)&h[8];
        } else {
            const short* pa = (const short*)Av + (long)blockIdx.z * sA;
#pragma unroll
            for (int p = 0; p < 2; p++)
                *(short8*)&As[sr4 + p * 64][sk4] =
                    *(const short8*)(pa + (long)(i0 + sr4 + p * 64) * lda + k0 + sk4);
        }
        if constexpr (BF32) {
            const float* pb = (const float*)Bv + (long)blockIdx.z * sB
                              + (long)(j0 + sr2) * ldb + k0 + sk2;
            float x[16];
            *(float4*)&x[0]  = *(const float4*)(pb + 0);
            *(float4*)&x[4]  = *(const float4*)(pb + 4);
            *(float4*)&x[8]  = *(const float4*)(pb + 8);
            *(float4*)&x[12] = *(const float4*)(pb + 12);
            unsigned short h[16];
#pragma unroll
            for (int t = 0; t < 16; t++) h[t] = f2bf(x[t]);
            *(short8*)&Bs[sr2][sk2]     = *(short8*)&h[0];
            *(short8*)&Bs[sr2][sk2 + 8] = *(short8*)&h[8];
        } else {
            const short* pb = (const short*)Bv + (long)blockIdx.z * sB;
#pragma unroll
            for (int p = 0; p < 2; p++)
                *(short8*)&Bs[sr4 + p * 64][sk4] =
                    *(const short8*)(pb + (long)(j0 + sr4 + p * 64) * ldb + k0 + sk4);
        }
        __syncthreads();
        short8 af[4], bf[4];
#pragma unroll
        for (int i = 0; i < 4; i++) af[i] = *(const short8*)&As[wr + i * 16 + fr][fq];
#pragma unroll
        for (int j = 0; j < 4; j++) bf[j] = *(const short8*)&Bs[wc + j * 16 + fr][fq];
#pragma unroll
        for (int i = 0; i < 4; i++)
#pragma unroll
            for (int j = 0; j < 4; j++)
                acc[i][j] = __builtin_amdgcn_mfma_f32_16x16x32_bf16(af[i], bf[j], acc[i][j], 0, 0, 0);
        __syncthreads();
    }

    float* Of = nullptr; unsigned short* Ob = nullptr;
    if constexpr (OUT_BF16) Ob = (unsigned short*)OutV + (long)blockIdx.z * sO;
    else                    Of = (float*)OutV + (long)blockIdx.z * sO;
    const int cr = (lane >> 4) * 4, cc = lane & 15;
#pragma unroll
    for (int i = 0; i < 4; i++) {
#pragma unroll
        for (int j = 0; j < 4; j++) {
            const int gj = j0 + wc + j * 16 + cc;
            float bb = 0.0f;
            if constexpr (BIAS) bb = bias[gj];
#pragma unroll
            for (int r = 0; r < 4; r++) {
                const int gi = i0 + wr + i * 16 + cr + r;
                float v = acc[i][j][r] + bb;
                long idx;
                if constexpr (OTRANS)
                    idx = (long)(gi >> 8) * 131072 + (long)gj * 256 + (gi & 255);
                else if constexpr (OPERM)
                    idx = (long)((gi & 63) * 128 + ((gi >> 6) & 15) * 8 + (gi >> 10)) * ldo + gj;
                else
                    idx = (long)gi * ldo + gj;
                if constexpr (OUT_BF16) Ob[idx] = f2bf(v);
                else                    Of[idx] = v;
            }
        }
    }
}

// ---------------------------------------------------------------------------
// Row reciprocal-norms from split pairs: rows 0..8191 -> q, 8192..10239 -> k.
// rs[row] = 1 / max(||row||, 1e-12).  One wave per 512-elem row.
// ---------------------------------------------------------------------------
__global__ __launch_bounds__(256) void rownorm(
    const unsigned short* __restrict__ qh, const unsigned short* __restrict__ ql,
    const unsigned short* __restrict__ kh, const unsigned short* __restrict__ kl,
    float* __restrict__ rs)
{
    const int row  = blockIdx.x * 4 + (threadIdx.x >> 6);
    const int lane = threadIdx.x & 63;
    const unsigned short *ph, *pl;
    long r;
    if (row < 8192) { ph = qh; pl = ql; r = row; }
    else            { ph = kh; pl = kl; r = row - 8192; }
    const long o = r * 512 + lane * 8;
    ushort4 h0 = *(const ushort4*)(ph + o),     h1 = *(const ushort4*)(ph + o + 4);
    ushort4 l0 = *(const ushort4*)(pl + o),     l1 = *(const ushort4*)(pl + o + 4);
    float ss = 0.0f;
    const unsigned short hv[8] = {h0.x, h0.y, h0.z, h0.w, h1.x, h1.y, h1.z, h1.w};
    const unsigned short lv[8] = {l0.x, l0.y, l0.z, l0.w, l1.x, l1.y, l1.z, l1.w};
#pragma unroll
    for (int i = 0; i < 8; i++) {
        const float v = bf2f(hv[i]) + bf2f(lv[i]);
        ss = fmaf(v, v, ss);
    }
#pragma unroll
    for (int off = 32; off; off >>= 1) ss += __shfl_xor(ss, off, 64);
    if (lane == 0) rs[row] = 1.0f / fmaxf(sqrtf(ss), 1e-12f);
}

// ---------------------------------------------------------------------------
// Sinkhorn, P layout + DPP reductions.  lane l = (m | 16g) holds
// K[m][16g+j], j=0..15.  u-step: 16 FMA + xor16/xor32 (2 DS).  v-step:
// column sums via 4 row_ror DPP stages (full-rate VALU, no LDS/readlane).
// Math identical to rounds 1-3 (multiplicative form of the reference).
// ---------------------------------------------------------------------------
#define ROR_STAGE(CTRL)                                                        \
    _Pragma("unroll")                                                          \
    for (int j = 0; j < 16; j++)                                               \
        t[j] += __int_as_float(__builtin_amdgcn_update_dpp(                    \
            0, __float_as_int(t[j]), CTRL, 0xf, 0xf, true));

__global__ __launch_bounds__(256) void sinkhorn3(
    const float* __restrict__ sim, float* __restrict__ score,
    unsigned short* __restrict__ Tt)
{
    const int lane = threadIdx.x & 63;
    const int wv   = threadIdx.x >> 6;
    const int bk   = blockIdx.x * 4 + wv;
    const int m = lane & 15, g = lane >> 4;
    const float* Sr = sim + (long)bk * 1024 + m * 64 + g * 16;

    float sv[16], Kv[16];
#pragma unroll
    for (int c4 = 0; c4 < 4; c4++) {
        float4 v = *(const float4*)(Sr + c4 * 4);
        sv[c4 * 4 + 0] = v.x; sv[c4 * 4 + 1] = v.y;
        sv[c4 * 4 + 2] = v.z; sv[c4 * 4 + 3] = v.w;
    }
#pragma unroll
    for (int j = 0; j < 16; j++) Kv[j] = __expf((sv[j] - 1.0f) * 20.0f);

    const float muP = 0.0625f + 1e-8f;      // exp(log(mu + 1e-8))
    const float nuP = 0.015625f + 1e-8f;
    float a = 0.0f;
    float bB[16];
#pragma unroll
    for (int j = 0; j < 16; j++) bB[j] = 1.0f;

#pragma unroll 1
    for (int it = 0; it < 100; it++) {
        // u-step: s_m = sum_n K[m,n] b_n
        float s0 = 0, s1 = 0, s2 = 0, s3 = 0;
#pragma unroll
        for (int j = 0; j < 4; j++) {
            s0 = fmaf(Kv[j],      bB[j],      s0);
            s1 = fmaf(Kv[4 + j],  bB[4 + j],  s1);
            s2 = fmaf(Kv[8 + j],  bB[8 + j],  s2);
            s3 = fmaf(Kv[12 + j], bB[12 + j], s3);
        }
        float s = (s0 + s1) + (s2 + s3);
        s += __shfl_xor(s, 16, 64);
        s += __shfl_xor(s, 32, 64);
        a = muP * fastrcp(s);
        // v-step: t_j = sum over the 16 m-lanes in this row of K[m,16g+j]*a_m
        float t[16];
#pragma unroll
        for (int j = 0; j < 16; j++) t[j] = Kv[j] * a;
        ROR_STAGE(0x121)   // row_ror:1
        ROR_STAGE(0x122)   // row_ror:2
        ROR_STAGE(0x124)   // row_ror:4
        ROR_STAGE(0x128)   // row_ror:8
#pragma unroll
        for (int j = 0; j < 16; j++) bB[j] = nuP * fastrcp(t[j]);
    }

    // outputs: score fp32 [bk][m][n]; T bf16 [b][mn][k'] for the T@V GEMM
    float* Sc = score + (long)bk * 1024 + m * 64 + g * 16;
    const long tb = (long)(bk >> 8) * 262144 + (bk & 255);
    const int nb = m * 64 + g * 16;
#pragma unroll
    for (int c4 = 0; c4 < 4; c4++) {
        float T0 = a * Kv[c4 * 4 + 0] * bB[c4 * 4 + 0];
        float T1 = a * Kv[c4 * 4 + 1] * bB[c4 * 4 + 1];
        float T2 = a * Kv[c4 * 4 + 2] * bB[c4 * 4 + 2];
        float T3 = a * Kv[c4 * 4 + 3] * bB[c4 * 4 + 3];
        float4 o;
        o.x = 1024.0f * sv[c4 * 4 + 0] * T0;
        o.y = 1024.0f * sv[c4 * 4 + 1] * T1;
        o.z = 1024.0f * sv[c4 * 4 + 2] * T2;
        o.w = 1024.0f * sv[c4 * 4 + 3] * T3;
        *(float4*)(Sc + c4 * 4) = o;
        Tt[tb + (long)(nb + c4 * 4 + 0) * 256] = f2bf(T0);
        Tt[tb + (long)(nb + c4 * 4 + 1) * 256] = f2bf(T1);
        Tt[tb + (long)(nb + c4 * 4 + 2) * 256] = f2bf(T2);
        Tt[tb + (long)(nb + c4 * 4 + 3) * 256] = f2bf(T3);
    }
}

extern "C" void kernel_launch(void* const* d_in, const int* in_sizes, int n_in,
                              void* d_out, int out_size, void* d_ws, size_t ws_size,
                              hipStream_t stream)
{
    (void)in_sizes; (void)n_in; (void)out_size; (void)ws_size;
    const float* xq = (const float*)d_in[0];
    const float* xk = (const float*)d_in[1];
    const float* xv = (const float*)d_in[2];
    const float* Wq = (const float*)d_in[3];
    const float* Wk = (const float*)d_in[4];
    const float* Wv = (const float*)d_in[5];
    const float* Wp = (const float*)d_in[6];
    const float* bp = (const float*)d_in[7];

    float* out_x     = (float*)d_out;           // (Nq,M,B,C) = 8192 x 512
    float* out_score = out_x + 8192L * 512;     // (B,K,M,Nq) = 2048 x 1024

    // workspace layout (42.1 MB of the proven 48 MB)
    char* W = (char*)d_ws;
    const long MB = 1 << 20;
    unsigned short* qh   = (unsigned short*)(W + 0);        // 8MB  [b][mn][c]
    unsigned short* ql   = (unsigned short*)(W + 8 * MB);   // 8MB
    unsigned short* kh   = (unsigned short*)(W + 16 * MB);  // 2MB  [b][k'][c]
    unsigned short* kl   = (unsigned short*)(W + 18 * MB);  // 2MB
    unsigned short* vt   = (unsigned short*)(W + 20 * MB);  // 2MB  [b][c][k']
    unsigned short* Tt   = (unsigned short*)(W + 22 * MB);  // 4MB  [b][mn][k']
    float*          simb = (float*)(W + 26 * MB);           // 8MB  [b][k'][mn]
    unsigned short* xpre = (unsigned short*)(W + 34 * MB);  // 8MB  [b][mn][c]
    float*          rs   = (float*)(W + 42 * MB);           // 40KB (q:8192, k:2048)

    const dim3 blk(256);

    // 1-2: q/k projections (fp32 in, split-bf16 pair out; q rows permuted)
    gemm_qkproj<true ><<<dim3(64, 4, 1), blk, 0, stream>>>(xq, Wq, qh, ql);
    gemm_qkproj<false><<<dim3(16, 4, 1), blk, 0, stream>>>(xk, Wk, kh, kl);

    // 3: reciprocal row norms (q then k)
    rownorm<<<2560, blk, 0, stream>>>(qh, ql, kh, kl, rs);

    // 4: v projection (fp32 ops cast in staging), transposed out vt[b][c][k']
    gemm_bf16<true, true, true, false, false, true><<<dim3(16, 4, 1), blk, 0, stream>>>(
        xv, Wv, nullptr, vt, 512, 512, 512, 0, 0, 0, 0);

    // 5: sim[b][k'][mn] = (k.q) * rs_k * rs_q   (bf16x3 + scale epilogue)
    gemm_sim<<<dim3(2, 8, 8), blk, 0, stream>>>(
        (const short*)kh, (const short*)kl, (const short*)qh, (const short*)ql,
        simb, rs);

    // 6: Sinkhorn -> score (out) + T bf16 [b][mn][k']
    sinkhorn3<<<512, blk, 0, stream>>>(simb, out_score, Tt);

    // 7: xpre[b][mn][c] = sum_k' T[b][mn][k'] * v[b][k'][c]
    gemm_bf16<false, false, false, false, false, true><<<dim3(8, 4, 8), blk, 0, stream>>>(
        Tt, vt, nullptr, xpre, 256, 256, 256, 512, 262144, 131072, 524288);

    // 8: x = xpre @ Wp^T + bp, rows (b,mn)->(n,m,b), fp32 out
    gemm_bf16<false, true, false, true, true, false><<<dim3(64, 4, 1), blk, 0, stream>>>(
        xpre, Wp, bp, out_x, 512, 512, 512, 512, 0, 0, 0);
}

// Round 5
// 226.699 us; speedup vs baseline: 1.3366x; 1.3366x over previous
//
#include <hip/hip_runtime.h>

// ---------------------------------------------------------------------------
// AttentionOT  (Nq=64, M=16, B=8, K=256, C=512)
//   Front (error-critical, feeds exp(20*sim)): bf16x3 split MFMA (Markidis).
//   Back half: plain bf16 MFMA.
//   Sinkhorn: dual rotated layouts + DPP row_ror all-gathers -> only 2 DS
//     ops per iteration (the 4-way cross-row reduce), 2 rcps per iteration.
//     Rotation direction is probed from HW at init (direction-proof).
//   6 dispatches: qkv-proj (fused, 384 blk) -> rownorm -> sim (64x64 tiles,
//     512 blk) -> sinkhorn -> T@V -> final proj.
// ---------------------------------------------------------------------------

typedef short   short8  __attribute__((ext_vector_type(8)));
typedef float   floatx4 __attribute__((ext_vector_type(4)));

static __device__ __forceinline__ float fastrcp(float x) {
    return __builtin_amdgcn_rcpf(x);
}
static __device__ __forceinline__ unsigned short f2bf(float f) {
    union { float f; unsigned u; } c; c.f = f;
    unsigned r = c.u + 0x7FFF + ((c.u >> 16) & 1);   // RNE
    return (unsigned short)(r >> 16);
}
static __device__ __forceinline__ float bf2f(unsigned short h) {
    union { unsigned u; float f; } c; c.u = (unsigned)h << 16;
    return c.f;
}

// row_ror:J move (old=0, all rows/banks, bound_ctrl: no invalid lanes anyway)
#define RRI(x, C) __builtin_amdgcn_update_dpp(0, (x), (C), 0xf, 0xf, true)
#define RRF(x, C) __int_as_float(RRI(__float_as_int(x), (C)))
// 16-slot intra-row all-gather of float s into d[0..15] (d[j] = rho_j(s))
#define GATH16(d, s) do { d[0] = (s);                                        \
    d[1]  = RRF((s), 0x121); d[2]  = RRF((s), 0x122);                        \
    d[3]  = RRF((s), 0x123); d[4]  = RRF((s), 0x124);                        \
    d[5]  = RRF((s), 0x125); d[6]  = RRF((s), 0x126);                        \
    d[7]  = RRF((s), 0x127); d[8]  = RRF((s), 0x128);                        \
    d[9]  = RRF((s), 0x129); d[10] = RRF((s), 0x12a);                        \
    d[11] = RRF((s), 0x12b); d[12] = RRF((s), 0x12c);                        \
    d[13] = RRF((s), 0x12d); d[14] = RRF((s), 0x12e);                        \
    d[15] = RRF((s), 0x12f); } while (0)

// ---------------------------------------------------------------------------
// Fused q/k/v projection, one dispatch.  blockIdx.x: 0..63 q, 64..79 k,
// 80..95 v.  q/k: bf16x3 split MFMA -> split bf16 pair out (q rows permuted
// (n*16+m)*8+b -> b*1024+m*64+n).  v: plain bf16 -> vt[b][c][k'] transposed.
// 128x128 tile, BK=32, fp32 inputs split/cast during LDS staging.
// ---------------------------------------------------------------------------
__global__ __launch_bounds__(256) void gemm_qkv(
    const float* __restrict__ xq, const float* __restrict__ xk,
    const float* __restrict__ xv, const float* __restrict__ Wq,
    const float* __restrict__ Wk, const float* __restrict__ Wv,
    unsigned short* __restrict__ qh, unsigned short* __restrict__ ql,
    unsigned short* __restrict__ kh, unsigned short* __restrict__ kl,
    unsigned short* __restrict__ vt)
{
    __shared__ __align__(16) short Ash[128][40];
    __shared__ __align__(16) short Asl[128][40];
    __shared__ __align__(16) short Bsh[128][40];
    __shared__ __align__(16) short Bsl[128][40];

    const int bx = blockIdx.x;
    const float *A, *Wt;
    int seg, arow0;
    if (bx < 64)      { A = xq; Wt = Wq; arow0 = bx * 128;        seg = 0; }
    else if (bx < 80) { A = xk; Wt = Wk; arow0 = (bx - 64) * 128; seg = 1; }
    else              { A = xv; Wt = Wv; arow0 = (bx - 80) * 128; seg = 2; }
    const bool split = (seg != 2);

    const int tid  = threadIdx.x;
    const int lane = tid & 63, wv = tid >> 6;
    const int wr = (wv >> 1) * 64, wc = (wv & 1) * 64;
    const int j0 = blockIdx.y * 128;

    floatx4 acc[4][4];
#pragma unroll
    for (int i = 0; i < 4; i++)
#pragma unroll
        for (int j = 0; j < 4; j++) acc[i][j] = {0.f, 0.f, 0.f, 0.f};

    const int sr = tid >> 1, sk = (tid & 1) * 16;
    const int fr = lane & 15, fq = (lane >> 4) * 8;

    for (int k0 = 0; k0 < 512; k0 += 32) {
        {
            const float* pa = A + (long)(arow0 + sr) * 512 + k0 + sk;
            float x[16];
            *(float4*)&x[0]  = *(const float4*)(pa + 0);
            *(float4*)&x[4]  = *(const float4*)(pa + 4);
            *(float4*)&x[8]  = *(const float4*)(pa + 8);
            *(float4*)&x[12] = *(const float4*)(pa + 12);
            unsigned short h[16];
#pragma unroll
            for (int t = 0; t < 16; t++) h[t] = f2bf(x[t]);
            *(short8*)&Ash[sr][sk]     = *(short8*)&h[0];
            *(short8*)&Ash[sr][sk + 8] = *(short8*)&h[8];
            if (split) {
                unsigned short l[16];
#pragma unroll
                for (int t = 0; t < 16; t++) l[t] = f2bf(x[t] - bf2f(h[t]));
                *(short8*)&Asl[sr][sk]     = *(short8*)&l[0];
                *(short8*)&Asl[sr][sk + 8] = *(short8*)&l[8];
            }
        }
        {
            const float* pb = Wt + (long)(j0 + sr) * 512 + k0 + sk;
            float x[16];
            *(float4*)&x[0]  = *(const float4*)(pb + 0);
            *(float4*)&x[4]  = *(const float4*)(pb + 4);
            *(float4*)&x[8]  = *(const float4*)(pb + 8);
            *(float4*)&x[12] = *(const float4*)(pb + 12);
            unsigned short h[16];
#pragma unroll
            for (int t = 0; t < 16; t++) h[t] = f2bf(x[t]);
            *(short8*)&Bsh[sr][sk]     = *(short8*)&h[0];
            *(short8*)&Bsh[sr][sk + 8] = *(short8*)&h[8];
            if (split) {
                unsigned short l[16];
#pragma unroll
                for (int t = 0; t < 16; t++) l[t] = f2bf(x[t] - bf2f(h[t]));
                *(short8*)&Bsl[sr][sk]     = *(short8*)&l[0];
                *(short8*)&Bsl[sr][sk + 8] = *(short8*)&l[8];
            }
        }
        __syncthreads();
        short8 ah[4], bh[4];
#pragma unroll
        for (int i = 0; i < 4; i++) ah[i] = *(const short8*)&Ash[wr + i * 16 + fr][fq];
#pragma unroll
        for (int j = 0; j < 4; j++) bh[j] = *(const short8*)&Bsh[wc + j * 16 + fr][fq];
        if (split) {
            short8 al[4], bl[4];
#pragma unroll
            for (int i = 0; i < 4; i++) al[i] = *(const short8*)&Asl[wr + i * 16 + fr][fq];
#pragma unroll
            for (int j = 0; j < 4; j++) bl[j] = *(const short8*)&Bsl[wc + j * 16 + fr][fq];
#pragma unroll
            for (int i = 0; i < 4; i++)
#pragma unroll
                for (int j = 0; j < 4; j++) {
                    acc[i][j] = __builtin_amdgcn_mfma_f32_16x16x32_bf16(ah[i], bh[j], acc[i][j], 0, 0, 0);
                    acc[i][j] = __builtin_amdgcn_mfma_f32_16x16x32_bf16(ah[i], bl[j], acc[i][j], 0, 0, 0);
                    acc[i][j] = __builtin_amdgcn_mfma_f32_16x16x32_bf16(al[i], bh[j], acc[i][j], 0, 0, 0);
                }
        } else {
#pragma unroll
            for (int i = 0; i < 4; i++)
#pragma unroll
                for (int j = 0; j < 4; j++)
                    acc[i][j] = __builtin_amdgcn_mfma_f32_16x16x32_bf16(ah[i], bh[j], acc[i][j], 0, 0, 0);
        }
        __syncthreads();
    }

    const int cr = (lane >> 4) * 4, cc = lane & 15;
#pragma unroll
    for (int i = 0; i < 4; i++)
#pragma unroll
        for (int j = 0; j < 4; j++) {
            const int gj = j0 + wc + j * 16 + cc;
#pragma unroll
            for (int r = 0; r < 4; r++) {
                const int gi = arow0 + wr + i * 16 + cr + r;   // segment-local
                const float v = acc[i][j][r];
                if (seg == 0) {
                    const long orow = (long)((gi & 7) * 1024 + ((gi >> 3) & 15) * 64 + (gi >> 7));
                    const unsigned short h = f2bf(v);
                    qh[orow * 512 + gj] = h;
                    ql[orow * 512 + gj] = f2bf(v - bf2f(h));
                } else if (seg == 1) {
                    const unsigned short h = f2bf(v);
                    kh[(long)gi * 512 + gj] = h;
                    kl[(long)gi * 512 + gj] = f2bf(v - bf2f(h));
                } else {
                    vt[(long)(gi >> 8) * 131072 + (long)gj * 256 + (gi & 255)] = f2bf(v);
                }
            }
        }
}

// ---------------------------------------------------------------------------
// sim GEMM, 64x64 tiles (512 blocks = 2/CU; the 128-tile version left half
// the machine idle at 128 blocks).  bf16x3 on split pairs, epilogue scale
// rs_k[i]*rs_q[j].  4 waves in 2x2, each 32x32 = 2x2 of 16x16x32.
// ---------------------------------------------------------------------------
__global__ __launch_bounds__(256) void gemm_sim64(
    const short* __restrict__ Ah, const short* __restrict__ Al,
    const short* __restrict__ Bh, const short* __restrict__ Bl,
    float* __restrict__ Out, const float* __restrict__ rs)
{
    const int z = blockIdx.z;
    Ah += (long)z * 131072;  Al += (long)z * 131072;
    Bh += (long)z * 524288;  Bl += (long)z * 524288;
    Out += (long)z * 262144;
    const float* rsq = rs + (long)z * 1024;
    const float* rsk = rs + 8192 + (long)z * 256;

    __shared__ __align__(16) short Ash[64][40];
    __shared__ __align__(16) short Asl[64][40];
    __shared__ __align__(16) short Bsh[64][40];
    __shared__ __align__(16) short Bsl[64][40];

    const int tid  = threadIdx.x;
    const int lane = tid & 63, wv = tid >> 6;
    const int wr = (wv >> 1) * 32, wc = (wv & 1) * 32;
    const int i0 = blockIdx.x * 64, j0 = blockIdx.y * 64;

    floatx4 acc[2][2];
#pragma unroll
    for (int i = 0; i < 2; i++)
#pragma unroll
        for (int j = 0; j < 2; j++) acc[i][j] = {0.f, 0.f, 0.f, 0.f};

    const int sr = tid >> 2, sch = (tid & 3) * 8;
    const int fr = lane & 15, fq = (lane >> 4) * 8;

    for (int k0 = 0; k0 < 512; k0 += 32) {
        const long ao = (long)(i0 + sr) * 512 + k0 + sch;
        const long bo = (long)(j0 + sr) * 512 + k0 + sch;
        *(short8*)&Ash[sr][sch] = *(const short8*)(Ah + ao);
        *(short8*)&Asl[sr][sch] = *(const short8*)(Al + ao);
        *(short8*)&Bsh[sr][sch] = *(const short8*)(Bh + bo);
        *(short8*)&Bsl[sr][sch] = *(const short8*)(Bl + bo);
        __syncthreads();
        short8 ah[2], al[2], bh[2], bl[2];
#pragma unroll
        for (int i = 0; i < 2; i++) {
            ah[i] = *(const short8*)&Ash[wr + i * 16 + fr][fq];
            al[i] = *(const short8*)&Asl[wr + i * 16 + fr][fq];
        }
#pragma unroll
        for (int j = 0; j < 2; j++) {
            bh[j] = *(const short8*)&Bsh[wc + j * 16 + fr][fq];
            bl[j] = *(const short8*)&Bsl[wc + j * 16 + fr][fq];
        }
#pragma unroll
        for (int i = 0; i < 2; i++)
#pragma unroll
            for (int j = 0; j < 2; j++) {
                acc[i][j] = __builtin_amdgcn_mfma_f32_16x16x32_bf16(ah[i], bh[j], acc[i][j], 0, 0, 0);
                acc[i][j] = __builtin_amdgcn_mfma_f32_16x16x32_bf16(ah[i], bl[j], acc[i][j], 0, 0, 0);
                acc[i][j] = __builtin_amdgcn_mfma_f32_16x16x32_bf16(al[i], bh[j], acc[i][j], 0, 0, 0);
            }
        __syncthreads();
    }

    const int cr = (lane >> 4) * 4, cc = lane & 15;
#pragma unroll
    for (int i = 0; i < 2; i++)
#pragma unroll
        for (int j = 0; j < 2; j++) {
            const int gj = j0 + wc + j * 16 + cc;
            const float sq = rsq[gj];
#pragma unroll
            for (int r = 0; r < 4; r++) {
                const int gi = i0 + wr + i * 16 + cr + r;
                Out[(long)gi * 1024 + gj] = acc[i][j][r] * rsk[gi] * sq;
            }
        }
}

// ---------------------------------------------------------------------------
// Plain bf16 MFMA GEMM (T@V and final proj), 128x128, BK=32.
// ---------------------------------------------------------------------------
template <bool BF32, bool BIAS, bool OPERM, bool OUT_BF16>
__global__ __launch_bounds__(256) void gemm_bf16(
    const void* __restrict__ Av, const void* __restrict__ Bv,
    const float* __restrict__ bias, void* __restrict__ OutV,
    int Kdim, int lda, int ldb, int ldo, long sA, long sB, long sO)
{
    __shared__ __align__(16) short As[128][40];
    __shared__ __align__(16) short Bs[128][40];

    const int tid  = threadIdx.x;
    const int lane = tid & 63, wv = tid >> 6;
    const int wr = (wv >> 1) * 64, wc = (wv & 1) * 64;
    const int i0 = blockIdx.x * 128, j0 = blockIdx.y * 128;

    floatx4 acc[4][4];
#pragma unroll
    for (int i = 0; i < 4; i++)
#pragma unroll
        for (int j = 0; j < 4; j++) acc[i][j] = {0.f, 0.f, 0.f, 0.f};

    const int sr2 = tid >> 1, sk2 = (tid & 1) * 16;
    const int sr4 = tid >> 2, sk4 = (tid & 3) * 8;
    const int fr = lane & 15, fq = (lane >> 4) * 8;

    for (int k0 = 0; k0 < Kdim; k0 += 32) {
        {
            const short* pa = (const short*)Av + (long)blockIdx.z * sA;
#pragma unroll
            for (int p = 0; p < 2; p++)
                *(short8*)&As[sr4 + p * 64][sk4] =
                    *(const short8*)(pa + (long)(i0 + sr4 + p * 64) * lda + k0 + sk4);
        }
        if constexpr (BF32) {
            const float* pb = (const float*)Bv + (long)blockIdx.z * sB
                              + (long)(j0 + sr2) * ldb + k0 + sk2;
            float x[16];
            *(float4*)&x[0]  = *(const float4*)(pb + 0);
            *(float4*)&x[4]  = *(const float4*)(pb + 4);
            *(float4*)&x[8]  = *(const float4*)(pb + 8);
            *(float4*)&x[12] = *(const float4*)(pb + 12);
            unsigned short h[16];
#pragma unroll
            for (int t = 0; t < 16; t++) h[t] = f2bf(x[t]);
            *(short8*)&Bs[sr2][sk2]     = *(short8*)&h[0];
            *(short8*)&Bs[sr2][sk2 + 8] = *(short8*)&h[8];
        } else {
            const short* pb = (const short*)Bv + (long)blockIdx.z * sB;
#pragma unroll
            for (int p = 0; p < 2; p++)
                *(short8*)&Bs[sr4 + p * 64][sk4] =
                    *(const short8*)(pb + (long)(j0 + sr4 + p * 64) * ldb + k0 + sk4);
        }
        __syncthreads();
        short8 af[4], bf[4];
#pragma unroll
        for (int i = 0; i < 4; i++) af[i] = *(const short8*)&As[wr + i * 16 + fr][fq];
#pragma unroll
        for (int j = 0; j < 4; j++) bf[j] = *(const short8*)&Bs[wc + j * 16 + fr][fq];
#pragma unroll
        for (int i = 0; i < 4; i++)
#pragma unroll
            for (int j = 0; j < 4; j++)
                acc[i][j] = __builtin_amdgcn_mfma_f32_16x16x32_bf16(af[i], bf[j], acc[i][j], 0, 0, 0);
        __syncthreads();
    }

    float* Of = nullptr; unsigned short* Ob = nullptr;
    if constexpr (OUT_BF16) Ob = (unsigned short*)OutV + (long)blockIdx.z * sO;
    else                    Of = (float*)OutV + (long)blockIdx.z * sO;
    const int cr = (lane >> 4) * 4, cc = lane & 15;
#pragma unroll
    for (int i = 0; i < 4; i++) {
#pragma unroll
        for (int j = 0; j < 4; j++) {
            const int gj = j0 + wc + j * 16 + cc;
            float bb = 0.0f;
            if constexpr (BIAS) bb = bias[gj];
#pragma unroll
            for (int r = 0; r < 4; r++) {
                const int gi = i0 + wr + i * 16 + cr + r;
                float v = acc[i][j][r] + bb;
                long idx;
                if constexpr (OPERM)
                    idx = (long)((gi & 63) * 128 + ((gi >> 6) & 15) * 8 + (gi >> 10)) * ldo + gj;
                else
                    idx = (long)gi * ldo + gj;
                if constexpr (OUT_BF16) Ob[idx] = f2bf(v);
                else                    Of[idx] = v;
            }
        }
    }
}

// ---------------------------------------------------------------------------
// Row reciprocal-norms from split pairs: rows 0..8191 q, 8192..10239 k.
// ---------------------------------------------------------------------------
__global__ __launch_bounds__(256) void rownorm(
    const unsigned short* __restrict__ qh, const unsigned short* __restrict__ ql,
    const unsigned short* __restrict__ kh, const unsigned short* __restrict__ kl,
    float* __restrict__ rs)
{
    const int row  = blockIdx.x * 4 + (threadIdx.x >> 6);
    const int lane = threadIdx.x & 63;
    const unsigned short *ph, *pl;
    long r;
    if (row < 8192) { ph = qh; pl = ql; r = row; }
    else            { ph = kh; pl = kl; r = row - 8192; }
    const long o = r * 512 + lane * 8;
    ushort4 h0 = *(const ushort4*)(ph + o), h1 = *(const ushort4*)(ph + o + 4);
    ushort4 l0 = *(const ushort4*)(pl + o), l1 = *(const ushort4*)(pl + o + 4);
    float ss = 0.0f;
    const unsigned short hv[8] = {h0.x, h0.y, h0.z, h0.w, h1.x, h1.y, h1.z, h1.w};
    const unsigned short lv[8] = {l0.x, l0.y, l0.z, l0.w, l1.x, l1.y, l1.z, l1.w};
#pragma unroll
    for (int i = 0; i < 8; i++) {
        const float v = bf2f(hv[i]) + bf2f(lv[i]);
        ss = fmaf(v, v, ss);
    }
#pragma unroll
    for (int off = 32; off; off >>= 1) ss += __shfl_xor(ss, off, 64);
    if (lane == 0) rs[row] = 1.0f / fmaxf(sqrtf(ss), 1e-12f);
}

// ---------------------------------------------------------------------------
// Sinkhorn (multiplicative form == reference log-domain update).
// Dual rotated layouts, one wave per problem:
//   P side  (lane = m|16g): K1[j] = K[m][16g + rho_j(m)]  (row chunks)
//   O side  (lane = n):     K2R[j] = K[rho_j(n&15)][n]    (columns)
// rho_j probed from HW (lane&15 through row_ror:j) -> direction-proof.
// Per iteration: u = 16 FMA + 2 shfl_xor (only DS ops) + rcp;
// a all-gather = 15 DPP movs; v = 16 FMA + rcp; b all-gather = 15 DPP movs.
// ---------------------------------------------------------------------------
__global__ __launch_bounds__(256) void sinkhorn5(
    const float* __restrict__ sim, float* __restrict__ score,
    unsigned short* __restrict__ Tt)
{
    const int lane = threadIdx.x & 63;
    const int bk   = blockIdx.x * 4 + (threadIdx.x >> 6);
    const float* S = sim + (long)bk * 1024;
    const int m = lane & 15, g = lane >> 4;

    // probe rho_j: pass (lane&15) through row_ror:j
    int idx[16];
    idx[0] = m;
    idx[1]  = RRI(m, 0x121); idx[2]  = RRI(m, 0x122); idx[3]  = RRI(m, 0x123);
    idx[4]  = RRI(m, 0x124); idx[5]  = RRI(m, 0x125); idx[6]  = RRI(m, 0x126);
    idx[7]  = RRI(m, 0x127); idx[8]  = RRI(m, 0x128); idx[9]  = RRI(m, 0x129);
    idx[10] = RRI(m, 0x12a); idx[11] = RRI(m, 0x12b); idx[12] = RRI(m, 0x12c);
    idx[13] = RRI(m, 0x12d); idx[14] = RRI(m, 0x12e); idx[15] = RRI(m, 0x12f);

    float K1[16], K2R[16], sv[16];
#pragma unroll
    for (int j = 0; j < 16; j++) {
        K1[j] = __expf((S[m * 64 + g * 16 + idx[j]] - 1.0f) * 20.0f);
        const float s_ = S[idx[j] * 64 + lane];
        sv[j]  = s_;
        K2R[j] = __expf((s_ - 1.0f) * 20.0f);
    }

    const float muP = 0.0625f + 1e-8f;      // exp(log(mu + 1e-8))
    const float nuP = 0.015625f + 1e-8f;
    float b = 1.0f;
    float aB[16], bB[16];
#pragma unroll
    for (int j = 0; j < 16; j++) bB[j] = 1.0f;

#pragma unroll 1
    for (int it = 0; it < 100; it++) {
        // u-step: s_m = sum_n K[m,n] b_n  (local dot + 4-way cross-row sum)
        float s0 = 0, s1 = 0, s2 = 0, s3 = 0;
#pragma unroll
        for (int j = 0; j < 4; j++) {
            s0 = fmaf(K1[j],      bB[j],      s0);
            s1 = fmaf(K1[4 + j],  bB[4 + j],  s1);
            s2 = fmaf(K1[8 + j],  bB[8 + j],  s2);
            s3 = fmaf(K1[12 + j], bB[12 + j], s3);
        }
        float s = (s0 + s1) + (s2 + s3);
        s += __shfl_xor(s, 16, 64);
        s += __shfl_xor(s, 32, 64);
        const float a = muP * fastrcp(s);   // every lane has a_{lane&15}
        GATH16(aB, a);                      // aB[j] = a_{rho_j}
        // v-step: t_n = sum_m K[m,n] a_m  (lane-local, rotated pairing)
        float t0 = 0, t1 = 0, t2 = 0, t3 = 0;
#pragma unroll
        for (int j = 0; j < 4; j++) {
            t0 = fmaf(K2R[j],      aB[j],      t0);
            t1 = fmaf(K2R[4 + j],  aB[4 + j],  t1);
            t2 = fmaf(K2R[8 + j],  aB[8 + j],  t2);
            t3 = fmaf(K2R[12 + j], aB[12 + j], t3);
        }
        b = nuP * fastrcp((t0 + t1) + (t2 + t3));
        GATH16(bB, b);                      // bB[j] = b_{16g + rho_j}
    }

    // epilogue on the O side: T[rho_j][lane] = a_{rho_j} * K[rho_j][lane] * b
    float* Sc = score + (long)bk * 1024;
    unsigned short* Tp = Tt + (long)(bk >> 8) * 262144 + (bk & 255);
#pragma unroll
    for (int j = 0; j < 16; j++) {
        const int row = idx[j];
        const float Tv = aB[j] * K2R[j] * b;
        Sc[row * 64 + lane] = 1024.0f * sv[j] * Tv;
        Tp[(long)(row * 64 + lane) * 256] = f2bf(Tv);
    }
}

extern "C" void kernel_launch(void* const* d_in, const int* in_sizes, int n_in,
                              void* d_out, int out_size, void* d_ws, size_t ws_size,
                              hipStream_t stream)
{
    (void)in_sizes; (void)n_in; (void)out_size; (void)ws_size;
    const float* xq = (const float*)d_in[0];
    const float* xk = (const float*)d_in[1];
    const float* xv = (const float*)d_in[2];
    const float* Wq = (const float*)d_in[3];
    const float* Wk = (const float*)d_in[4];
    const float* Wv = (const float*)d_in[5];
    const float* Wp = (const float*)d_in[6];
    const float* bp = (const float*)d_in[7];

    float* out_x     = (float*)d_out;           // (Nq,M,B,C) = 8192 x 512
    float* out_score = out_x + 8192L * 512;     // (B,K,M,Nq) = 2048 x 1024

    // workspace layout (42.1 MB of the proven 48 MB)
    char* W = (char*)d_ws;
    const long MB = 1 << 20;
    unsigned short* qh   = (unsigned short*)(W + 0);        // 8MB [b][mn][c]
    unsigned short* ql   = (unsigned short*)(W + 8 * MB);   // 8MB
    unsigned short* kh   = (unsigned short*)(W + 16 * MB);  // 2MB [b][k'][c]
    unsigned short* kl   = (unsigned short*)(W + 18 * MB);  // 2MB
    unsigned short* vt   = (unsigned short*)(W + 20 * MB);  // 2MB [b][c][k']
    unsigned short* Tt   = (unsigned short*)(W + 22 * MB);  // 4MB [b][mn][k']
    float*          simb = (float*)(W + 26 * MB);           // 8MB [b][k'][mn]
    unsigned short* xpre = (unsigned short*)(W + 34 * MB);  // 8MB [b][mn][c]
    float*          rs   = (float*)(W + 42 * MB);           // 40KB

    const dim3 blk(256);

    // 1: fused q/k/v projections (one dispatch, 384 blocks)
    gemm_qkv<<<dim3(96, 4), blk, 0, stream>>>(
        xq, xk, xv, Wq, Wk, Wv, qh, ql, kh, kl, vt);

    // 2: reciprocal row norms
    rownorm<<<2560, blk, 0, stream>>>(qh, ql, kh, kl, rs);

    // 3: sim[b][k'][mn] = (k.q) * rs_k * rs_q  (64x64 tiles, 512 blocks)
    gemm_sim64<<<dim3(4, 16, 8), blk, 0, stream>>>(
        (const short*)kh, (const short*)kl, (const short*)qh, (const short*)ql,
        simb, rs);

    // 4: Sinkhorn -> score (out) + T bf16 [b][mn][k']
    sinkhorn5<<<512, blk, 0, stream>>>(simb, out_score, Tt);

    // 5: xpre[b][mn][c] = sum_k' T[b][mn][k'] * v[b][k'][c]
    gemm_bf16<false, false, false, true><<<dim3(8, 4, 8), blk, 0, stream>>>(
        Tt, vt, nullptr, xpre, 256, 256, 256, 512, 262144, 131072, 524288);

    // 6: x = xpre @ Wp^T + bp, rows (b,mn)->(n,m,b), fp32 out
    gemm_bf16<true, true, true, false><<<dim3(64, 4), blk, 0, stream>>>(
        xpre, Wp, bp, out_x, 512, 512, 512, 512, 0, 0, 0);
}

// Round 6
// 217.997 us; speedup vs baseline: 1.3900x; 1.0399x over previous
//
#include <hip/hip_runtime.h>

// ---------------------------------------------------------------------------
// AttentionOT  (Nq=64, M=16, B=8, K=256, C=512)
//   Front (error-critical, feeds exp(20*sim)): bf16x3 split MFMA (Markidis),
//     operands PRE-SPLIT by a memory-bound prep pass (round-5 fused the
//     fp32->split conversion into the K-loop: 78us, MfmaUtil 8%).
//   Back half: plain bf16 MFMA, weights precast.
//   Sinkhorn: rotated dual layouts + DPP (round-5 kernel, verified).
//   7 dispatches: prep -> qkv -> rownorm -> sim -> sinkhorn -> T@V -> proj.
// ---------------------------------------------------------------------------

typedef short   short8  __attribute__((ext_vector_type(8)));
typedef float   floatx4 __attribute__((ext_vector_type(4)));

static __device__ __forceinline__ float fastrcp(float x) {
    return __builtin_amdgcn_rcpf(x);
}
static __device__ __forceinline__ unsigned short f2bf(float f) {
    union { float f; unsigned u; } c; c.f = f;
    unsigned r = c.u + 0x7FFF + ((c.u >> 16) & 1);   // RNE
    return (unsigned short)(r >> 16);
}
static __device__ __forceinline__ float bf2f(unsigned short h) {
    union { unsigned u; float f; } c; c.u = (unsigned)h << 16;
    return c.f;
}

#define RRI(x, C) __builtin_amdgcn_update_dpp(0, (x), (C), 0xf, 0xf, true)
#define RRF(x, C) __int_as_float(RRI(__float_as_int(x), (C)))
#define GATH16(d, s) do { d[0] = (s);                                        \
    d[1]  = RRF((s), 0x121); d[2]  = RRF((s), 0x122);                        \
    d[3]  = RRF((s), 0x123); d[4]  = RRF((s), 0x124);                        \
    d[5]  = RRF((s), 0x125); d[6]  = RRF((s), 0x126);                        \
    d[7]  = RRF((s), 0x127); d[8]  = RRF((s), 0x128);                        \
    d[9]  = RRF((s), 0x129); d[10] = RRF((s), 0x12a);                        \
    d[11] = RRF((s), 0x12b); d[12] = RRF((s), 0x12c);                        \
    d[13] = RRF((s), 0x12d); d[14] = RRF((s), 0x12e);                        \
    d[15] = RRF((s), 0x12f); } while (0)

// ---------------------------------------------------------------------------
// prep: fp32 -> bf16 split (xq,xk,Wq,Wk) / cast (xv,Wv,Wp).  One dispatch,
// one float4 per thread, memory-bound.
// ---------------------------------------------------------------------------
__global__ __launch_bounds__(256) void prep(
    const float* __restrict__ xq, const float* __restrict__ xk,
    const float* __restrict__ xv, const float* __restrict__ Wq,
    const float* __restrict__ Wk, const float* __restrict__ Wv,
    const float* __restrict__ Wp,
    unsigned short* __restrict__ xqh, unsigned short* __restrict__ xql,
    unsigned short* __restrict__ xkh, unsigned short* __restrict__ xkl,
    unsigned short* __restrict__ xvb,
    unsigned short* __restrict__ wqh, unsigned short* __restrict__ wql,
    unsigned short* __restrict__ wkh, unsigned short* __restrict__ wkl,
    unsigned short* __restrict__ wvb, unsigned short* __restrict__ wpb)
{
    const int b = blockIdx.x;
    const float* src; unsigned short *dh, *dl; long base;
    if (b < 4096)      { src = xq; dh = xqh; dl = xql;     base = (long)b * 256; }
    else if (b < 5120) { src = xk; dh = xkh; dl = xkl;     base = (long)(b - 4096) * 256; }
    else if (b < 6144) { src = xv; dh = xvb; dl = nullptr; base = (long)(b - 5120) * 256; }
    else if (b < 6400) { src = Wq; dh = wqh; dl = wql;     base = (long)(b - 6144) * 256; }
    else if (b < 6656) { src = Wk; dh = wkh; dl = wkl;     base = (long)(b - 6400) * 256; }
    else if (b < 6912) { src = Wv; dh = wvb; dl = nullptr; base = (long)(b - 6656) * 256; }
    else               { src = Wp; dh = wpb; dl = nullptr; base = (long)(b - 6912) * 256; }
    const long i = base + threadIdx.x;
    float4 v = ((const float4*)src)[i];
    ushort4 h;
    h.x = f2bf(v.x); h.y = f2bf(v.y); h.z = f2bf(v.z); h.w = f2bf(v.w);
    ((ushort4*)dh)[i] = h;
    if (dl) {
        ushort4 l;
        l.x = f2bf(v.x - bf2f(h.x)); l.y = f2bf(v.y - bf2f(h.y));
        l.z = f2bf(v.z - bf2f(h.z)); l.w = f2bf(v.w - bf2f(h.w));
        ((ushort4*)dl)[i] = l;
    }
}

// ---------------------------------------------------------------------------
// Fused q/k/v projection on PRECONVERTED bf16 operands.  blockIdx.x:
// 0..63 q (split3), 64..79 k (split3), 80..95 v (plain).  128x128, BK=32.
// Epilogues: q -> qh/ql permuted rows; k -> kh/kl; v -> vt[b][c][k'] via
// LDS transpose (coalesced 16B stores; round-5 wrote 2B at 512B stride).
// ---------------------------------------------------------------------------
__global__ __launch_bounds__(256) void gemm_qkv2(
    const unsigned short* __restrict__ xqh, const unsigned short* __restrict__ xql,
    const unsigned short* __restrict__ xkh, const unsigned short* __restrict__ xkl,
    const unsigned short* __restrict__ xvb,
    const unsigned short* __restrict__ wqh, const unsigned short* __restrict__ wql,
    const unsigned short* __restrict__ wkh, const unsigned short* __restrict__ wkl,
    const unsigned short* __restrict__ wvb,
    unsigned short* __restrict__ qh, unsigned short* __restrict__ ql,
    unsigned short* __restrict__ kh, unsigned short* __restrict__ kl,
    unsigned short* __restrict__ vt)
{
    __shared__ __align__(16) short LB[20480];          // 40 KB
    short (*Ash)[40] = (short(*)[40])(LB);
    short (*Asl)[40] = (short(*)[40])(LB + 5120);
    short (*Bsh)[40] = (short(*)[40])(LB + 10240);
    short (*Bsl)[40] = (short(*)[40])(LB + 15360);

    const int bx = blockIdx.x;
    const unsigned short *Ah, *Al, *Bh, *Bl;
    int seg, arow0;
    if (bx < 64)      { Ah = xqh; Al = xql; Bh = wqh; Bl = wql; arow0 = bx * 128;        seg = 0; }
    else if (bx < 80) { Ah = xkh; Al = xkl; Bh = wkh; Bl = wkl; arow0 = (bx - 64) * 128; seg = 1; }
    else              { Ah = xvb; Al = xvb; Bh = wvb; Bl = wvb; arow0 = (bx - 80) * 128; seg = 2; }
    const bool split = (seg != 2);

    const int tid  = threadIdx.x;
    const int lane = tid & 63, wv = tid >> 6;
    const int wr = (wv >> 1) * 64, wc = (wv & 1) * 64;
    const int j0 = blockIdx.y * 128;

    floatx4 acc[4][4];
#pragma unroll
    for (int i = 0; i < 4; i++)
#pragma unroll
        for (int j = 0; j < 4; j++) acc[i][j] = {0.f, 0.f, 0.f, 0.f};

    const int sr = tid >> 2, sch = (tid & 3) * 8;
    const int fr = lane & 15, fq = (lane >> 4) * 8;

    for (int k0 = 0; k0 < 512; k0 += 32) {
#pragma unroll
        for (int p = 0; p < 2; p++) {
            const int r = sr + p * 64;
            const long ao = (long)(arow0 + r) * 512 + k0 + sch;
            const long bo = (long)(j0 + r) * 512 + k0 + sch;
            *(short8*)&Ash[r][sch] = *(const short8*)(Ah + ao);
            *(short8*)&Bsh[r][sch] = *(const short8*)(Bh + bo);
            if (split) {
                *(short8*)&Asl[r][sch] = *(const short8*)(Al + ao);
                *(short8*)&Bsl[r][sch] = *(const short8*)(Bl + bo);
            }
        }
        __syncthreads();
        short8 ah[4], bh[4];
#pragma unroll
        for (int i = 0; i < 4; i++) ah[i] = *(const short8*)&Ash[wr + i * 16 + fr][fq];
#pragma unroll
        for (int j = 0; j < 4; j++) bh[j] = *(const short8*)&Bsh[wc + j * 16 + fr][fq];
        if (split) {
            short8 al[4], bl[4];
#pragma unroll
            for (int i = 0; i < 4; i++) al[i] = *(const short8*)&Asl[wr + i * 16 + fr][fq];
#pragma unroll
            for (int j = 0; j < 4; j++) bl[j] = *(const short8*)&Bsl[wc + j * 16 + fr][fq];
#pragma unroll
            for (int i = 0; i < 4; i++)
#pragma unroll
                for (int j = 0; j < 4; j++) {
                    acc[i][j] = __builtin_amdgcn_mfma_f32_16x16x32_bf16(ah[i], bh[j], acc[i][j], 0, 0, 0);
                    acc[i][j] = __builtin_amdgcn_mfma_f32_16x16x32_bf16(ah[i], bl[j], acc[i][j], 0, 0, 0);
                    acc[i][j] = __builtin_amdgcn_mfma_f32_16x16x32_bf16(al[i], bh[j], acc[i][j], 0, 0, 0);
                }
        } else {
#pragma unroll
            for (int i = 0; i < 4; i++)
#pragma unroll
                for (int j = 0; j < 4; j++)
                    acc[i][j] = __builtin_amdgcn_mfma_f32_16x16x32_bf16(ah[i], bh[j], acc[i][j], 0, 0, 0);
        }
        __syncthreads();
    }

    const int cr = (lane >> 4) * 4, cc = lane & 15;
    if (seg == 2) {
        // LDS transpose: S2[c_local][k'_local], rows padded to 136 shorts
        short (*S2)[136] = (short(*)[136])LB;
#pragma unroll
        for (int i = 0; i < 4; i++)
#pragma unroll
            for (int j = 0; j < 4; j++)
#pragma unroll
                for (int r = 0; r < 4; r++)
                    S2[wc + j * 16 + cc][wr + i * 16 + cr + r] =
                        (short)f2bf(acc[i][j][r]);
        __syncthreads();
        const int orow = tid >> 1;            // c_local 0..127
        const int os   = (tid & 1) * 64;      // k'_local chunk
        unsigned short* dst = vt + (long)(arow0 >> 8) * 131072
                            + (long)(j0 + orow) * 256 + (arow0 & 255) + os;
#pragma unroll
        for (int c8 = 0; c8 < 8; c8++)
            *(short8*)(dst + c8 * 8) = *(const short8*)&S2[orow][os + c8 * 8];
    } else {
#pragma unroll
        for (int i = 0; i < 4; i++)
#pragma unroll
            for (int j = 0; j < 4; j++) {
                const int gj = j0 + wc + j * 16 + cc;
#pragma unroll
                for (int r = 0; r < 4; r++) {
                    const int gi = arow0 + wr + i * 16 + cr + r;
                    const float v = acc[i][j][r];
                    const unsigned short h = f2bf(v);
                    const unsigned short lo = f2bf(v - bf2f(h));
                    if (seg == 0) {
                        const long orow = (long)((gi & 7) * 1024 + ((gi >> 3) & 15) * 64 + (gi >> 7));
                        qh[orow * 512 + gj] = h;
                        ql[orow * 512 + gj] = lo;
                    } else {
                        kh[(long)gi * 512 + gj] = h;
                        kl[(long)gi * 512 + gj] = lo;
                    }
                }
            }
    }
}

// ---------------------------------------------------------------------------
// sim GEMM, 64x64 tiles (512 blocks), bf16x3 on split pairs, epilogue scale
// rs_k[i]*rs_q[j].  (round-5 kernel, unchanged)
// ---------------------------------------------------------------------------
__global__ __launch_bounds__(256) void gemm_sim64(
    const short* __restrict__ Ah, const short* __restrict__ Al,
    const short* __restrict__ Bh, const short* __restrict__ Bl,
    float* __restrict__ Out, const float* __restrict__ rs)
{
    const int z = blockIdx.z;
    Ah += (long)z * 131072;  Al += (long)z * 131072;
    Bh += (long)z * 524288;  Bl += (long)z * 524288;
    Out += (long)z * 262144;
    const float* rsq = rs + (long)z * 1024;
    const float* rsk = rs + 8192 + (long)z * 256;

    __shared__ __align__(16) short Ash[64][40];
    __shared__ __align__(16) short Asl[64][40];
    __shared__ __align__(16) short Bsh[64][40];
    __shared__ __align__(16) short Bsl[64][40];

    const int tid  = threadIdx.x;
    const int lane = tid & 63, wv = tid >> 6;
    const int wr = (wv >> 1) * 32, wc = (wv & 1) * 32;
    const int i0 = blockIdx.x * 64, j0 = blockIdx.y * 64;

    floatx4 acc[2][2];
#pragma unroll
    for (int i = 0; i < 2; i++)
#pragma unroll
        for (int j = 0; j < 2; j++) acc[i][j] = {0.f, 0.f, 0.f, 0.f};

    const int sr = tid >> 2, sch = (tid & 3) * 8;
    const int fr = lane & 15, fq = (lane >> 4) * 8;

    for (int k0 = 0; k0 < 512; k0 += 32) {
        const long ao = (long)(i0 + sr) * 512 + k0 + sch;
        const long bo = (long)(j0 + sr) * 512 + k0 + sch;
        *(short8*)&Ash[sr][sch] = *(const short8*)(Ah + ao);
        *(short8*)&Asl[sr][sch] = *(const short8*)(Al + ao);
        *(short8*)&Bsh[sr][sch] = *(const short8*)(Bh + bo);
        *(short8*)&Bsl[sr][sch] = *(const short8*)(Bl + bo);
        __syncthreads();
        short8 ah[2], al[2], bh[2], bl[2];
#pragma unroll
        for (int i = 0; i < 2; i++) {
            ah[i] = *(const short8*)&Ash[wr + i * 16 + fr][fq];
            al[i] = *(const short8*)&Asl[wr + i * 16 + fr][fq];
        }
#pragma unroll
        for (int j = 0; j < 2; j++) {
            bh[j] = *(const short8*)&Bsh[wc + j * 16 + fr][fq];
            bl[j] = *(const short8*)&Bsl[wc + j * 16 + fr][fq];
        }
#pragma unroll
        for (int i = 0; i < 2; i++)
#pragma unroll
            for (int j = 0; j < 2; j++) {
                acc[i][j] = __builtin_amdgcn_mfma_f32_16x16x32_bf16(ah[i], bh[j], acc[i][j], 0, 0, 0);
                acc[i][j] = __builtin_amdgcn_mfma_f32_16x16x32_bf16(ah[i], bl[j], acc[i][j], 0, 0, 0);
                acc[i][j] = __builtin_amdgcn_mfma_f32_16x16x32_bf16(al[i], bh[j], acc[i][j], 0, 0, 0);
            }
        __syncthreads();
    }

    const int cr = (lane >> 4) * 4, cc = lane & 15;
#pragma unroll
    for (int i = 0; i < 2; i++)
#pragma unroll
        for (int j = 0; j < 2; j++) {
            const int gj = j0 + wc + j * 16 + cc;
            const float sq = rsq[gj];
#pragma unroll
            for (int r = 0; r < 4; r++) {
                const int gi = i0 + wr + i * 16 + cr + r;
                Out[(long)gi * 1024 + gj] = acc[i][j][r] * rsk[gi] * sq;
            }
        }
}

// ---------------------------------------------------------------------------
// Plain bf16 MFMA GEMM (T@V and final proj), 128x128, BK=32, pure bf16.
// ---------------------------------------------------------------------------
template <bool BIAS, bool OPERM, bool OUT_BF16>
__global__ __launch_bounds__(256) void gemm_bf16(
    const short* __restrict__ A, const short* __restrict__ B,
    const float* __restrict__ bias, void* __restrict__ OutV,
    int Kdim, int lda, int ldb, int ldo, long sA, long sB, long sO)
{
    __shared__ __align__(16) short As[128][40];
    __shared__ __align__(16) short Bs[128][40];

    const int tid  = threadIdx.x;
    const int lane = tid & 63, wv = tid >> 6;
    const int wr = (wv >> 1) * 64, wc = (wv & 1) * 64;
    const int i0 = blockIdx.x * 128, j0 = blockIdx.y * 128;

    floatx4 acc[4][4];
#pragma unroll
    for (int i = 0; i < 4; i++)
#pragma unroll
        for (int j = 0; j < 4; j++) acc[i][j] = {0.f, 0.f, 0.f, 0.f};

    const int sr = tid >> 2, sk = (tid & 3) * 8;
    const int fr = lane & 15, fq = (lane >> 4) * 8;
    const short* pa = A + (long)blockIdx.z * sA;
    const short* pb = B + (long)blockIdx.z * sB;

    for (int k0 = 0; k0 < Kdim; k0 += 32) {
#pragma unroll
        for (int p = 0; p < 2; p++) {
            *(short8*)&As[sr + p * 64][sk] =
                *(const short8*)(pa + (long)(i0 + sr + p * 64) * lda + k0 + sk);
            *(short8*)&Bs[sr + p * 64][sk] =
                *(const short8*)(pb + (long)(j0 + sr + p * 64) * ldb + k0 + sk);
        }
        __syncthreads();
        short8 af[4], bf[4];
#pragma unroll
        for (int i = 0; i < 4; i++) af[i] = *(const short8*)&As[wr + i * 16 + fr][fq];
#pragma unroll
        for (int j = 0; j < 4; j++) bf[j] = *(const short8*)&Bs[wc + j * 16 + fr][fq];
#pragma unroll
        for (int i = 0; i < 4; i++)
#pragma unroll
            for (int j = 0; j < 4; j++)
                acc[i][j] = __builtin_amdgcn_mfma_f32_16x16x32_bf16(af[i], bf[j], acc[i][j], 0, 0, 0);
        __syncthreads();
    }

    float* Of = nullptr; unsigned short* Ob = nullptr;
    if constexpr (OUT_BF16) Ob = (unsigned short*)OutV + (long)blockIdx.z * sO;
    else                    Of = (float*)OutV + (long)blockIdx.z * sO;
    const int cr = (lane >> 4) * 4, cc = lane & 15;
#pragma unroll
    for (int i = 0; i < 4; i++) {
#pragma unroll
        for (int j = 0; j < 4; j++) {
            const int gj = j0 + wc + j * 16 + cc;
            float bb = 0.0f;
            if constexpr (BIAS) bb = bias[gj];
#pragma unroll
            for (int r = 0; r < 4; r++) {
                const int gi = i0 + wr + i * 16 + cr + r;
                float v = acc[i][j][r] + bb;
                long idx;
                if constexpr (OPERM)
                    idx = (long)((gi & 63) * 128 + ((gi >> 6) & 15) * 8 + (gi >> 10)) * ldo + gj;
                else
                    idx = (long)gi * ldo + gj;
                if constexpr (OUT_BF16) Ob[idx] = f2bf(v);
                else                    Of[idx] = v;
            }
        }
    }
}

// ---------------------------------------------------------------------------
// Row reciprocal-norms from split pairs: rows 0..8191 q, 8192..10239 k.
// ---------------------------------------------------------------------------
__global__ __launch_bounds__(256) void rownorm(
    const unsigned short* __restrict__ qh, const unsigned short* __restrict__ ql,
    const unsigned short* __restrict__ kh, const unsigned short* __restrict__ kl,
    float* __restrict__ rs)
{
    const int row  = blockIdx.x * 4 + (threadIdx.x >> 6);
    const int lane = threadIdx.x & 63;
    const unsigned short *ph, *pl;
    long r;
    if (row < 8192) { ph = qh; pl = ql; r = row; }
    else            { ph = kh; pl = kl; r = row - 8192; }
    const long o = r * 512 + lane * 8;
    ushort4 h0 = *(const ushort4*)(ph + o), h1 = *(const ushort4*)(ph + o + 4);
    ushort4 l0 = *(const ushort4*)(pl + o), l1 = *(const ushort4*)(pl + o + 4);
    float ss = 0.0f;
    const unsigned short hv[8] = {h0.x, h0.y, h0.z, h0.w, h1.x, h1.y, h1.z, h1.w};
    const unsigned short lv[8] = {l0.x, l0.y, l0.z, l0.w, l1.x, l1.y, l1.z, l1.w};
#pragma unroll
    for (int i = 0; i < 8; i++) {
        const float v = bf2f(hv[i]) + bf2f(lv[i]);
        ss = fmaf(v, v, ss);
    }
#pragma unroll
    for (int off = 32; off; off >>= 1) ss += __shfl_xor(ss, off, 64);
    if (lane == 0) rs[row] = 1.0f / fmaxf(sqrtf(ss), 1e-12f);
}

// ---------------------------------------------------------------------------
// Sinkhorn, rotated dual layouts + DPP (round-5 kernel, verified).
// ---------------------------------------------------------------------------
__global__ __launch_bounds__(256) void sinkhorn5(
    const float* __restrict__ sim, float* __restrict__ score,
    unsigned short* __restrict__ Tt)
{
    const int lane = threadIdx.x & 63;
    const int bk   = blockIdx.x * 4 + (threadIdx.x >> 6);
    const float* S = sim + (long)bk * 1024;
    const int m = lane & 15, g = lane >> 4;

    int idx[16];
    idx[0] = m;
    idx[1]  = RRI(m, 0x121); idx[2]  = RRI(m, 0x122); idx[3]  = RRI(m, 0x123);
    idx[4]  = RRI(m, 0x124); idx[5]  = RRI(m, 0x125); idx[6]  = RRI(m, 0x126);
    idx[7]  = RRI(m, 0x127); idx[8]  = RRI(m, 0x128); idx[9]  = RRI(m, 0x129);
    idx[10] = RRI(m, 0x12a); idx[11] = RRI(m, 0x12b); idx[12] = RRI(m, 0x12c);
    idx[13] = RRI(m, 0x12d); idx[14] = RRI(m, 0x12e); idx[15] = RRI(m, 0x12f);

    float K1[16], K2R[16], sv[16];
#pragma unroll
    for (int j = 0; j < 16; j++) {
        K1[j] = __expf((S[m * 64 + g * 16 + idx[j]] - 1.0f) * 20.0f);
        const float s_ = S[idx[j] * 64 + lane];
        sv[j]  = s_;
        K2R[j] = __expf((s_ - 1.0f) * 20.0f);
    }

    const float muP = 0.0625f + 1e-8f;
    const float nuP = 0.015625f + 1e-8f;
    float b = 1.0f;
    float aB[16], bB[16];
#pragma unroll
    for (int j = 0; j < 16; j++) bB[j] = 1.0f;

#pragma unroll 1
    for (int it = 0; it < 100; it++) {
        float s0 = 0, s1 = 0, s2 = 0, s3 = 0;
#pragma unroll
        for (int j = 0; j < 4; j++) {
            s0 = fmaf(K1[j],      bB[j],      s0);
            s1 = fmaf(K1[4 + j],  bB[4 + j],  s1);
            s2 = fmaf(K1[8 + j],  bB[8 + j],  s2);
            s3 = fmaf(K1[12 + j], bB[12 + j], s3);
        }
        float s = (s0 + s1) + (s2 + s3);
        s += __shfl_xor(s, 16, 64);
        s += __shfl_xor(s, 32, 64);
        const float a = muP * fastrcp(s);
        GATH16(aB, a);
        float t0 = 0, t1 = 0, t2 = 0, t3 = 0;
#pragma unroll
        for (int j = 0; j < 4; j++) {
            t0 = fmaf(K2R[j],      aB[j],      t0);
            t1 = fmaf(K2R[4 + j],  aB[4 + j],  t1);
            t2 = fmaf(K2R[8 + j],  aB[8 + j],  t2);
            t3 = fmaf(K2R[12 + j], aB[12 + j], t3);
        }
        b = nuP * fastrcp((t0 + t1) + (t2 + t3));
        GATH16(bB, b);
    }

    float* Sc = score + (long)bk * 1024;
    unsigned short* Tp = Tt + (long)(bk >> 8) * 262144 + (bk & 255);
#pragma unroll
    for (int j = 0; j < 16; j++) {
        const int row = idx[j];
        const float Tv = aB[j] * K2R[j] * b;
        Sc[row * 64 + lane] = 1024.0f * sv[j] * Tv;
        Tp[(long)(row * 64 + lane) * 256] = f2bf(Tv);
    }
}

extern "C" void kernel_launch(void* const* d_in, const int* in_sizes, int n_in,
                              void* d_out, int out_size, void* d_ws, size_t ws_size,
                              hipStream_t stream)
{
    (void)in_sizes; (void)n_in; (void)out_size; (void)ws_size;
    const float* xq = (const float*)d_in[0];
    const float* xk = (const float*)d_in[1];
    const float* xv = (const float*)d_in[2];
    const float* Wq = (const float*)d_in[3];
    const float* Wk = (const float*)d_in[4];
    const float* Wv = (const float*)d_in[5];
    const float* Wp = (const float*)d_in[6];
    const float* bp = (const float*)d_in[7];

    float* out_x     = (float*)d_out;           // (Nq,M,B,C) = 8192 x 512
    float* out_score = out_x + 8192L * 512;     // (B,K,M,Nq) = 2048 x 1024

    // workspace (47.1 MB of the proven 48 MB); regions reused across phases
    char* W = (char*)d_ws;
    const long MB = 1 << 20;
    unsigned short* qh   = (unsigned short*)(W + 0);        // 8MB [b][mn][c]
    unsigned short* ql   = (unsigned short*)(W + 8 * MB);   // 8MB
    unsigned short* xq_h = (unsigned short*)(W + 16 * MB);  // 8MB, dead after qkv
    float*          simb = (float*)(W + 16 * MB);           // 8MB (reuse)
    unsigned short* xq_l = (unsigned short*)(W + 24 * MB);  // 8MB, dead after qkv
    unsigned short* xpre = (unsigned short*)(W + 24 * MB);  // 8MB (reuse)
    unsigned short* xk_h = (unsigned short*)(W + 32 * MB);  // 2MB, dead after qkv
    unsigned short* xk_l = (unsigned short*)(W + 34 * MB);  // 2MB
    unsigned short* Tt   = (unsigned short*)(W + 32 * MB);  // 4MB (reuse)
    unsigned short* xv_b = (unsigned short*)(W + 36 * MB);  // 2MB
    unsigned short* kh   = (unsigned short*)(W + 38 * MB);  // 2MB [b][k'][c]
    unsigned short* kl   = (unsigned short*)(W + 40 * MB);  // 2MB
    unsigned short* vt   = (unsigned short*)(W + 42 * MB);  // 2MB [b][c][k']
    unsigned short* wqh  = (unsigned short*)(W + 44 * MB);
    unsigned short* wql  = (unsigned short*)(W + 44 * MB + 1 * 524288);
    unsigned short* wkh  = (unsigned short*)(W + 44 * MB + 2 * 524288);
    unsigned short* wkl  = (unsigned short*)(W + 44 * MB + 3 * 524288);
    unsigned short* wvb  = (unsigned short*)(W + 44 * MB + 4 * 524288);
    unsigned short* wpb  = (unsigned short*)(W + 44 * MB + 5 * 524288);
    float*          rs   = (float*)(W + 47 * MB);           // 40KB

    const dim3 blk(256);

    // 1: precast/split all fp32 operands (memory-bound, one dispatch)
    prep<<<7168, blk, 0, stream>>>(xq, xk, xv, Wq, Wk, Wv, Wp,
                                   xq_h, xq_l, xk_h, xk_l, xv_b,
                                   wqh, wql, wkh, wkl, wvb, wpb);

    // 2: fused q/k/v projections on bf16 operands
    gemm_qkv2<<<dim3(96, 4), blk, 0, stream>>>(
        xq_h, xq_l, xk_h, xk_l, xv_b, wqh, wql, wkh, wkl, wvb,
        qh, ql, kh, kl, vt);

    // 3: reciprocal row norms
    rownorm<<<2560, blk, 0, stream>>>(qh, ql, kh, kl, rs);

    // 4: sim[b][k'][mn] = (k.q) * rs_k * rs_q
    gemm_sim64<<<dim3(4, 16, 8), blk, 0, stream>>>(
        (const short*)kh, (const short*)kl, (const short*)qh, (const short*)ql,
        simb, rs);

    // 5: Sinkhorn -> score (out) + T bf16 [b][mn][k']
    sinkhorn5<<<512, blk, 0, stream>>>(simb, out_score, Tt);

    // 6: xpre[b][mn][c] = sum_k' T[b][mn][k'] * v[b][k'][c]
    gemm_bf16<false, false, true><<<dim3(8, 4, 8), blk, 0, stream>>>(
        (const short*)Tt, (const short*)vt, nullptr, xpre,
        256, 256, 256, 512, 262144, 131072, 524288);

    // 7: x = xpre @ Wp^T + bp, rows (b,mn)->(n,m,b), fp32 out
    gemm_bf16<true, true, false><<<dim3(64, 4), blk, 0, stream>>>(
        (const short*)xpre, (const short*)wpb, bp, out_x,
        512, 512, 512, 512, 0, 0, 0);
}